// Round 6
// baseline (780.582 us; speedup 1.0000x reference)
//
#include <hip/hip_runtime.h>
#include <math.h>

#define D 128

typedef __bf16 bf16x8 __attribute__((ext_vector_type(8)));
typedef float f32x4 __attribute__((ext_vector_type(4)));

__device__ __forceinline__ unsigned short f2bf(float f) {
    unsigned u = __float_as_uint(f);
    return (unsigned short)((u + 0x7FFFu + ((u >> 16) & 1u)) >> 16);
}
__device__ __forceinline__ float bf2f(unsigned short h) {
    return __uint_as_float(((unsigned)h) << 16);
}
__device__ __forceinline__ bf16x8 pack8(const unsigned* v) {
    union { uint4 u; bf16x8 b; } c;
    c.u.x = v[0]; c.u.y = v[1]; c.u.z = v[2]; c.u.w = v[3];
    return c.b;
}

__device__ __forceinline__ int lbound(const int* __restrict__ a, int L, int v) {
    int lo = 0, hi = L;
    while (lo < hi) { int m = (lo + hi) >> 1; if (a[m] < v) lo = m + 1; else hi = m; }
    return lo;
}

// Wave-level segmented atomic accumulate; all 64 lanes of the wave converged.
__device__ __forceinline__ void seg_atomic(float* __restrict__ seg, int g, float v, bool valid) {
    float tv = valid ? v : 0.f;
    float s = tv;
#pragma unroll
    for (int o = 1; o < 64; o <<= 1) s += __shfl_xor(s, o, 64);
    unsigned long long vb = __ballot(valid);
    if (vb == 0ULL) return;
    int g0 = __shfl(g, __ffsll((unsigned long long)vb) - 1, 64);
    unsigned long long ub = __ballot((!valid) || (g == g0));
    const int lane = (int)(threadIdx.x & 63u);
    if (ub == ~0ULL) {
        if (lane == 0) atomicAdd(seg + g0, s);
    } else {
        if (valid) atomicAdd(seg + g, tv);
    }
}

__device__ __forceinline__ void wave_add(float* __restrict__ dst, float v) {
    float s = v;
#pragma unroll
    for (int o = 1; o < 64; o <<= 1) s += __shfl_xor(s, o, 64);
    if ((threadIdx.x & 63u) == 0) atomicAdd(dst, s);
}

// Positive-edge kernel: both heads, M=64 edges/tile, 8 waves.
// Waves 0-3: W1-head cols 32w..32w+32 (plain bf16).  Waves 4-7: We1-head (hi+lo bf16).
// Gather is software-pipelined 2-deep: edge indices prefetched 2 tiles ahead,
// x-row FIRST halves (one 128B line per thread) 1 tile ahead (issued right after
// barrier G so they land during the MFMA phase); second halves loaded at convert
// time from the now-hot line.
__global__ __launch_bounds__(512, 4)
void pos_kernel(const float* __restrict__ x,
                const int* __restrict__ ei, const int* __restrict__ ebatch,
                const float* __restrict__ W1, const float* __restrict__ b1,
                const float* __restrict__ W2, const float* __restrict__ b2,
                const float* __restrict__ We1, const float* __restrict__ be1,
                const float* __restrict__ We2, const float* __restrict__ be2,
                const float* __restrict__ attr,
                float* __restrict__ posSum, float* __restrict__ tot1,
                int E, int ntiles) {
    __shared__ float smem[9104];
    unsigned short* As  = (unsigned short*)smem;            // 1024 slots x 16 B (16 KB)
    unsigned short* Hbf = (unsigned short*)(smem + 4096);   // H1 relu'd: [64][136] bf16
    float* posP = smem + 8448;                              // [4][64] We-head partials
    float* b1s  = smem + 8704;
    float* be1s = smem + 8832;
    float* We2s = smem + 8960;
    float* b2s  = smem + 9088;
    float* be2s = smem + 9096;

    const int t   = (int)threadIdx.x;
    const int wv  = t >> 6;
    const int l   = t & 63;
    const int sub = l & 15;
    const int q   = l >> 4;
    const int e_  = t >> 3;          // gather edge 0..63
    const int ks  = t & 7;           // gather k-slice
    const int k0  = ks * 16;

    // ---- gather pipeline prologue
    int cS = 0, cD = 0, nS = 0, nD = 0;
    float4 P0s, P1s, P0d, P1d;
    {
        const int tile0 = (int)blockIdx.x;
        const int Ei0 = tile0 * 64 + e_;
        if (tile0 < ntiles && Ei0 < E) {
            cS = ei[Ei0]; cD = ei[E + Ei0];
            const float4* ps = (const float4*)(x + (size_t)cS * D + k0);
            const float4* pd = (const float4*)(x + (size_t)cD * D + k0);
            P0s = ps[0]; P1s = ps[1]; P0d = pd[0]; P1d = pd[1];
        }
        const int t1  = tile0 + (int)gridDim.x;
        const int Ei1 = t1 * 64 + e_;
        if (t1 < ntiles && Ei1 < E) { nS = ei[Ei1]; nD = ei[E + Ei1]; }
    }

    // ---- B fragments, direct per-lane loads from global (one-time; W is L2-hot)
    bf16x8 Bh[2][4];   // wv<4: W1 cols; wv>=4: We1-hi cols
    bf16x8 Bl[2][4];   // wv>=4: We1-lo; wv<4: Bl[0][kt] = W2 fragment (layer-2 GEMM)
    {
        const float* Wsrc = (wv < 4) ? W1 : We1;
        const int jb = (wv & 3) * 32;
#pragma unroll
        for (int ct = 0; ct < 2; ct++) {
#pragma unroll
            for (int kt = 0; kt < 4; kt++) {
                unsigned vh[4], vl[4];
#pragma unroll
                for (int jj = 0; jj < 4; jj++) {
                    const float f0 = Wsrc[(kt * 32 + q * 8 + 2 * jj)     * D + jb + ct * 16 + sub];
                    const float f1 = Wsrc[(kt * 32 + q * 8 + 2 * jj + 1) * D + jb + ct * 16 + sub];
                    const unsigned short h0 = f2bf(f0), h1 = f2bf(f1);
                    vh[jj] = (unsigned)h0 | ((unsigned)h1 << 16);
                    const unsigned short g0 = f2bf(f0 - bf2f(h0));
                    const unsigned short g1 = f2bf(f1 - bf2f(h1));
                    vl[jj] = (unsigned)g0 | ((unsigned)g1 << 16);
                }
                Bh[ct][kt] = pack8(vh);
                if (wv >= 4) Bl[ct][kt] = pack8(vl);
            }
        }
        if (wv < 4) {   // W2 frags (B-operand of layer-2 GEMM), cols 7..15 zero
#pragma unroll
            for (int kt = 0; kt < 4; kt++) {
                const int kb = kt * 32 + q * 8;
                unsigned v[4];
#pragma unroll
                for (int jj = 0; jj < 4; jj++) {
                    unsigned short h0 = (sub < 7) ? f2bf(W2[(kb + 2 * jj) * 7 + sub]) : (unsigned short)0;
                    unsigned short h1 = (sub < 7) ? f2bf(W2[(kb + 2 * jj + 1) * 7 + sub]) : (unsigned short)0;
                    v[jj] = (unsigned)h0 | ((unsigned)h1 << 16);
                }
                Bl[0][kt] = pack8(v);
            }
        }
    }
    if (t < 128) { b1s[t] = b1[t]; be1s[t] = be1[t]; We2s[t] = We2[t]; }
    if (t < 7) b2s[t] = b2[t];
    if (t == 7) be2s[0] = be2[0];
    __syncthreads();

    float lpAcc = 0.f;

    for (int tile = (int)blockIdx.x; tile < ntiles; tile += (int)gridDim.x) {
        const int base = tile * 64;
        // ---- convert prefetched gather -> bf16 -> swizzled A frags
        {
            const int Ei = base + e_;
            unsigned v[8];
            if (Ei < E) {
                const float4* ps = (const float4*)(x + (size_t)cS * D + k0);
                const float4* pd = (const float4*)(x + (size_t)cD * D + k0);
                const float4 S2 = ps[2], S3 = ps[3];      // same 128B line as P0s/P1s
                const float4 D2 = pd[2], D3 = pd[3];
                const float4 sa[4] = {P0s, P1s, S2, S3};
                const float4 da[4] = {P0d, P1d, D2, D3};
#pragma unroll
                for (int i2 = 0; i2 < 4; i2++) {
                    const float4 a = sa[i2], b = da[i2];
                    unsigned short p0 = f2bf(fmaxf(a.x * b.x, 0.f));
                    unsigned short p1 = f2bf(fmaxf(a.y * b.y, 0.f));
                    unsigned short p2 = f2bf(fmaxf(a.z * b.z, 0.f));
                    unsigned short p3 = f2bf(fmaxf(a.w * b.w, 0.f));
                    v[i2 * 2]     = (unsigned)p0 | ((unsigned)p1 << 16);
                    v[i2 * 2 + 1] = (unsigned)p2 | ((unsigned)p3 << 16);
                }
            } else {
#pragma unroll
                for (int i2 = 0; i2 < 8; i2++) v[i2] = 0u;
            }
            const int slot = ((e_ >> 4) * 4 + (ks >> 1)) * 64 + (ks & 1) * 32 + (e_ & 15);
            uint4 u0; u0.x = v[0]; u0.y = v[1]; u0.z = v[2]; u0.w = v[3];
            uint4 u1; u1.x = v[4]; u1.y = v[5]; u1.z = v[6]; u1.w = v[7];
            *(uint4*)(As + slot * 8) = u0;
            *(uint4*)(As + (slot + 16) * 8) = u1;
        }
        __syncthreads();                    // barrier G
        // ---- prefetch: rows for tile+grid (idx already in regs), idx for tile+2*grid
        {
            const int nt  = tile + (int)gridDim.x;
            const int EiN = nt * 64 + e_;
            if (nt < ntiles && EiN < E) {
                cS = nS; cD = nD;
                const float4* ps = (const float4*)(x + (size_t)cS * D + k0);
                const float4* pd = (const float4*)(x + (size_t)cD * D + k0);
                P0s = ps[0]; P1s = ps[1]; P0d = pd[0]; P1d = pd[1];
            }
            const int nt2 = tile + 2 * (int)gridDim.x;
            const int Ei2 = nt2 * 64 + e_;
            if (nt2 < ntiles && Ei2 < E) { nS = ei[Ei2]; nD = ei[E + Ei2]; }
        }
        // ---- layer-1 MFMAs + per-wave epilogue
#pragma unroll
        for (int mt = 0; mt < 4; mt++) {
            bf16x8 a0 = *(const bf16x8*)(As + ((mt * 4 + 0) * 64 + l) * 8);
            bf16x8 a1 = *(const bf16x8*)(As + ((mt * 4 + 1) * 64 + l) * 8);
            bf16x8 a2 = *(const bf16x8*)(As + ((mt * 4 + 2) * 64 + l) * 8);
            bf16x8 a3 = *(const bf16x8*)(As + ((mt * 4 + 3) * 64 + l) * 8);
            float zp0 = 0.f, zp1 = 0.f, zp2 = 0.f, zp3 = 0.f;
#pragma unroll
            for (int ct = 0; ct < 2; ct++) {
                f32x4 c = {0.f, 0.f, 0.f, 0.f};
                c = __builtin_amdgcn_mfma_f32_16x16x32_bf16(a0, Bh[ct][0], c, 0, 0, 0);
                c = __builtin_amdgcn_mfma_f32_16x16x32_bf16(a1, Bh[ct][1], c, 0, 0, 0);
                c = __builtin_amdgcn_mfma_f32_16x16x32_bf16(a2, Bh[ct][2], c, 0, 0, 0);
                c = __builtin_amdgcn_mfma_f32_16x16x32_bf16(a3, Bh[ct][3], c, 0, 0, 0);
                if (wv >= 4) {
                    c = __builtin_amdgcn_mfma_f32_16x16x32_bf16(a0, Bl[ct][0], c, 0, 0, 0);
                    c = __builtin_amdgcn_mfma_f32_16x16x32_bf16(a1, Bl[ct][1], c, 0, 0, 0);
                    c = __builtin_amdgcn_mfma_f32_16x16x32_bf16(a2, Bl[ct][2], c, 0, 0, 0);
                    c = __builtin_amdgcn_mfma_f32_16x16x32_bf16(a3, Bl[ct][3], c, 0, 0, 0);
                }
                const int jloc = (wv & 3) * 32 + ct * 16 + sub;
                if (wv < 4) {
                    const float bb = b1s[jloc];
#pragma unroll
                    for (int r = 0; r < 4; r++)
                        Hbf[(mt * 16 + q * 4 + r) * 136 + jloc] = f2bf(fmaxf(c[r] + bb, 0.f));
                } else {
                    const float bb = be1s[jloc], ww = We2s[jloc];
                    zp0 += fmaxf(c[0] + bb, 0.f) * ww;
                    zp1 += fmaxf(c[1] + bb, 0.f) * ww;
                    zp2 += fmaxf(c[2] + bb, 0.f) * ww;
                    zp3 += fmaxf(c[3] + bb, 0.f) * ww;
                }
            }
            if (wv >= 4) {
#pragma unroll
                for (int o = 1; o < 16; o <<= 1) {
                    zp0 += __shfl_xor(zp0, o, 64);
                    zp1 += __shfl_xor(zp1, o, 64);
                    zp2 += __shfl_xor(zp2, o, 64);
                    zp3 += __shfl_xor(zp3, o, 64);
                }
                if (sub < 4) {
                    float vv = (sub == 0) ? zp0 : (sub == 1) ? zp1 : (sub == 2) ? zp2 : zp3;
                    posP[(wv - 4) * 64 + mt * 16 + q * 4 + sub] = vv;
                }
            }
        }
        __syncthreads();                    // barrier M
        // ---- layer 2 (waves 0-3): S = Hbf @ W2frag via MFMA; lane sub==7 does We-head
        if (wv < 4) {
            f32x4 cS2 = {0.f, 0.f, 0.f, 0.f};
#pragma unroll
            for (int jt = 0; jt < 4; jt++) {
                bf16x8 hf = *(const bf16x8*)(Hbf + (wv * 16 + sub) * 136 + jt * 32 + q * 8);
                cS2 = __builtin_amdgcn_mfma_f32_16x16x32_bf16(hf, Bl[0][jt], cS2, 0, 0, 0);
            }
            float bceP[4] = {0.f, 0.f, 0.f, 0.f};
            float lpP[4]  = {0.f, 0.f, 0.f, 0.f};
#pragma unroll
            for (int r = 0; r < 4; r++) {
                const int e = wv * 16 + q * 4 + r;
                const int Ei = base + e;
                const bool vE = (Ei < E);
                if (sub < 7 && vE) {
                    const float z = cS2[r] + b2s[sub];
                    const float p = 1.f / (1.f + expf(-z));
                    const float ta = attr[(size_t)Ei * 9 + sub];
                    bceP[r] = -(ta * fmaxf(logf(p), -100.f)
                              + (1.f - ta) * fmaxf(log1pf(-p), -100.f));
                } else if (sub == 7 && vE) {
                    const float zp = posP[e] + posP[64 + e] + posP[128 + e] + posP[192 + e] + be2s[0];
                    const float pp = 1.f / (1.f + expf(-zp));
                    lpP[r]  = -fmaxf(logf(pp), -100.f);
                    bceP[r] = lpP[r];
                }
            }
#pragma unroll
            for (int o = 1; o < 16; o <<= 1)
#pragma unroll
                for (int r = 0; r < 4; r++) {
                    bceP[r] += __shfl_xor(bceP[r], o, 64);
                    lpP[r]  += __shfl_xor(lpP[r],  o, 64);
                }
            const float lossSel = (sub == 0) ? bceP[0] : (sub == 1) ? bceP[1]
                                : (sub == 2) ? bceP[2] : bceP[3];
            const float lpSel   = (sub == 0) ? lpP[0] : (sub == 1) ? lpP[1]
                                : (sub == 2) ? lpP[2] : lpP[3];
            const int eW  = wv * 16 + q * 4 + (sub & 3);
            const int EiW = base + eW;
            const bool act = (sub < 4) && (EiW < E);
            const int g = ebatch[EiW < E ? EiW : E - 1];
            seg_atomic(posSum, g, lossSel, act);
            lpAcc += act ? lpSel : 0.f;
        }
    }
    if (wv < 4) wave_add(tot1, lpAcc);
}

// Negative-edge kernel: We-head only. M=64, 8 waves x 16 cols, We1 hi+lo.
__global__ __launch_bounds__(512, 4)
void neg_kernel(const float* __restrict__ x,
                const int* __restrict__ ei, const int* __restrict__ ebatch,
                const float* __restrict__ We1, const float* __restrict__ be1,
                const float* __restrict__ We2, const float* __restrict__ be2,
                float* __restrict__ negSum, float* __restrict__ tot2,
                int E, int ntiles) {
    __shared__ float smem[4872];
    unsigned short* As = (unsigned short*)smem;     // 16 KB A frags
    float* negP = smem + 4096;                      // [8][64]
    float* be1s = smem + 4608;
    float* We2s = smem + 4736;
    float* be2s = smem + 4864;

    const int t   = (int)threadIdx.x;
    const int wv  = t >> 6;
    const int l   = t & 63;
    const int sub = l & 15;
    const int q   = l >> 4;
    const int e_  = t >> 3;
    const int ks  = t & 7;
    const int k0  = ks * 16;

    // ---- gather pipeline prologue
    int cS = 0, cD = 0, nS = 0, nD = 0;
    float4 P0s, P1s, P0d, P1d;
    {
        const int tile0 = (int)blockIdx.x;
        const int Ei0 = tile0 * 64 + e_;
        if (tile0 < ntiles && Ei0 < E) {
            cS = ei[Ei0]; cD = ei[E + Ei0];
            const float4* ps = (const float4*)(x + (size_t)cS * D + k0);
            const float4* pd = (const float4*)(x + (size_t)cD * D + k0);
            P0s = ps[0]; P1s = ps[1]; P0d = pd[0]; P1d = pd[1];
        }
        const int t1  = tile0 + (int)gridDim.x;
        const int Ei1 = t1 * 64 + e_;
        if (t1 < ntiles && Ei1 < E) { nS = ei[Ei1]; nD = ei[E + Ei1]; }
    }

    // ---- B fragments, direct per-lane loads
    bf16x8 Bh[4], Bl[4];
    {
        const int jb = wv * 16;
#pragma unroll
        for (int kt = 0; kt < 4; kt++) {
            unsigned vh[4], vl[4];
#pragma unroll
            for (int jj = 0; jj < 4; jj++) {
                const float f0 = We1[(kt * 32 + q * 8 + 2 * jj)     * D + jb + sub];
                const float f1 = We1[(kt * 32 + q * 8 + 2 * jj + 1) * D + jb + sub];
                const unsigned short h0 = f2bf(f0), h1 = f2bf(f1);
                vh[jj] = (unsigned)h0 | ((unsigned)h1 << 16);
                const unsigned short g0 = f2bf(f0 - bf2f(h0));
                const unsigned short g1 = f2bf(f1 - bf2f(h1));
                vl[jj] = (unsigned)g0 | ((unsigned)g1 << 16);
            }
            Bh[kt] = pack8(vh);
            Bl[kt] = pack8(vl);
        }
    }
    if (t < 128) { be1s[t] = be1[t]; We2s[t] = We2[t]; }
    if (t == 128) be2s[0] = be2[0];
    __syncthreads();

    float lnAcc = 0.f;

    for (int tile = (int)blockIdx.x; tile < ntiles; tile += (int)gridDim.x) {
        const int base = tile * 64;
        {
            const int Ei = base + e_;
            unsigned v[8];
            if (Ei < E) {
                const float4* ps = (const float4*)(x + (size_t)cS * D + k0);
                const float4* pd = (const float4*)(x + (size_t)cD * D + k0);
                const float4 S2 = ps[2], S3 = ps[3];
                const float4 D2 = pd[2], D3 = pd[3];
                const float4 sa[4] = {P0s, P1s, S2, S3};
                const float4 da[4] = {P0d, P1d, D2, D3};
#pragma unroll
                for (int i2 = 0; i2 < 4; i2++) {
                    const float4 a = sa[i2], b = da[i2];
                    unsigned short p0 = f2bf(fmaxf(a.x * b.x, 0.f));
                    unsigned short p1 = f2bf(fmaxf(a.y * b.y, 0.f));
                    unsigned short p2 = f2bf(fmaxf(a.z * b.z, 0.f));
                    unsigned short p3 = f2bf(fmaxf(a.w * b.w, 0.f));
                    v[i2 * 2]     = (unsigned)p0 | ((unsigned)p1 << 16);
                    v[i2 * 2 + 1] = (unsigned)p2 | ((unsigned)p3 << 16);
                }
            } else {
#pragma unroll
                for (int i2 = 0; i2 < 8; i2++) v[i2] = 0u;
            }
            const int slot = ((e_ >> 4) * 4 + (ks >> 1)) * 64 + (ks & 1) * 32 + (e_ & 15);
            uint4 u0; u0.x = v[0]; u0.y = v[1]; u0.z = v[2]; u0.w = v[3];
            uint4 u1; u1.x = v[4]; u1.y = v[5]; u1.z = v[6]; u1.w = v[7];
            *(uint4*)(As + slot * 8) = u0;
            *(uint4*)(As + (slot + 16) * 8) = u1;
        }
        __syncthreads();
        {
            const int nt  = tile + (int)gridDim.x;
            const int EiN = nt * 64 + e_;
            if (nt < ntiles && EiN < E) {
                cS = nS; cD = nD;
                const float4* ps = (const float4*)(x + (size_t)cS * D + k0);
                const float4* pd = (const float4*)(x + (size_t)cD * D + k0);
                P0s = ps[0]; P1s = ps[1]; P0d = pd[0]; P1d = pd[1];
            }
            const int nt2 = tile + 2 * (int)gridDim.x;
            const int Ei2 = nt2 * 64 + e_;
            if (nt2 < ntiles && Ei2 < E) { nS = ei[Ei2]; nD = ei[E + Ei2]; }
        }
        const int j = wv * 16 + sub;
        const float bb = be1s[j], ww = We2s[j];
#pragma unroll
        for (int mt = 0; mt < 4; mt++) {
            bf16x8 a0 = *(const bf16x8*)(As + ((mt * 4 + 0) * 64 + l) * 8);
            bf16x8 a1 = *(const bf16x8*)(As + ((mt * 4 + 1) * 64 + l) * 8);
            bf16x8 a2 = *(const bf16x8*)(As + ((mt * 4 + 2) * 64 + l) * 8);
            bf16x8 a3 = *(const bf16x8*)(As + ((mt * 4 + 3) * 64 + l) * 8);
            f32x4 c = {0.f, 0.f, 0.f, 0.f};
            c = __builtin_amdgcn_mfma_f32_16x16x32_bf16(a0, Bh[0], c, 0, 0, 0);
            c = __builtin_amdgcn_mfma_f32_16x16x32_bf16(a1, Bh[1], c, 0, 0, 0);
            c = __builtin_amdgcn_mfma_f32_16x16x32_bf16(a2, Bh[2], c, 0, 0, 0);
            c = __builtin_amdgcn_mfma_f32_16x16x32_bf16(a3, Bh[3], c, 0, 0, 0);
            c = __builtin_amdgcn_mfma_f32_16x16x32_bf16(a0, Bl[0], c, 0, 0, 0);
            c = __builtin_amdgcn_mfma_f32_16x16x32_bf16(a1, Bl[1], c, 0, 0, 0);
            c = __builtin_amdgcn_mfma_f32_16x16x32_bf16(a2, Bl[2], c, 0, 0, 0);
            c = __builtin_amdgcn_mfma_f32_16x16x32_bf16(a3, Bl[3], c, 0, 0, 0);
            float zp0 = fmaxf(c[0] + bb, 0.f) * ww;
            float zp1 = fmaxf(c[1] + bb, 0.f) * ww;
            float zp2 = fmaxf(c[2] + bb, 0.f) * ww;
            float zp3 = fmaxf(c[3] + bb, 0.f) * ww;
#pragma unroll
            for (int o = 1; o < 16; o <<= 1) {
                zp0 += __shfl_xor(zp0, o, 64);
                zp1 += __shfl_xor(zp1, o, 64);
                zp2 += __shfl_xor(zp2, o, 64);
                zp3 += __shfl_xor(zp3, o, 64);
            }
            if (sub < 4) {
                float vv = (sub == 0) ? zp0 : (sub == 1) ? zp1 : (sub == 2) ? zp2 : zp3;
                negP[wv * 64 + mt * 16 + q * 4 + sub] = vv;
            }
        }
        __syncthreads();
        if (wv == 0) {
            const int Ei = base + l;
            const bool valid = (Ei < E);
            float zp = be2s[0];
#pragma unroll
            for (int i = 0; i < 8; i++) zp += negP[i * 64 + l];
            float lossN = 0.f;
            if (valid) {
                const float pp = 1.f / (1.f + expf(-zp));
                lossN = -fmaxf(log1pf(-pp), -100.f);
            }
            const int g = ebatch[Ei < E ? Ei : E - 1];
            seg_atomic(negSum, g, lossN, valid);
            lnAcc += valid ? lossN : 0.f;
        }
    }
    if (wv == 0) wave_add(tot2, lnAcc);
}

__global__ __launch_bounds__(256)
void kl_kernel(const float* __restrict__ xm, const float* __restrict__ xs,
               const int* __restrict__ batch, float* __restrict__ klSum, int N) {
    const int n = (int)(blockIdx.x * 256 + threadIdx.x);
    const bool valid = (n < N);
    float kl = 0.f;
    int g = 0;
    if (valid) {
        const float4* m4 = (const float4*)(xm + (size_t)n * D);
        const float4* s4 = (const float4*)(xs + (size_t)n * D);
        float s = 0.f;
        // Clamp log at -1e4 (< log(min denormal)): bit-identical for sd > 0,
        // finite at sd == 0 where the reference is +inf (threshold inf).
#pragma unroll 8
        for (int i = 0; i < 32; i++) {
            const float4 m = m4[i];
            const float4 sd = s4[i];
            s += 1.f + 2.f * fmaxf(logf(sd.x), -1e4f) - m.x * m.x - sd.x * sd.x;
            s += 1.f + 2.f * fmaxf(logf(sd.y), -1e4f) - m.y * m.y - sd.y * sd.y;
            s += 1.f + 2.f * fmaxf(logf(sd.z), -1e4f) - m.z * m.z - sd.z * sd.z;
            s += 1.f + 2.f * fmaxf(logf(sd.w), -1e4f) - m.w * m.w - sd.w * sd.w;
        }
        kl = -0.5f * s;
        g = batch[n];
    }
    seg_atomic(klSum, g, kl, valid);
}

__global__ __launch_bounds__(256)
void final_kernel(const int* __restrict__ eib, const int* __restrict__ einb,
                  const int* __restrict__ nbatch,
                  const float* __restrict__ posSum, const float* __restrict__ negSum,
                  const float* __restrict__ klSum,
                  float* __restrict__ tot, int E, int N, int G) {
    const int g = (int)(blockIdx.x * blockDim.x + threadIdx.x);
    float lg = 0.f;
    if (g < G) {
        const int cP = lbound(eib, E, g + 1) - lbound(eib, E, g);
        const int cN = lbound(einb, E, g + 1) - lbound(einb, E, g);
        const int cB = lbound(nbatch, N, g + 1) - lbound(nbatch, N, g);
        const float fp = fmaxf((float)cP, 1.f);
        const float fn = fmaxf((float)cN, 1.f);
        const float fb = fmaxf((float)cB, 1.f);
        lg = posSum[g] / fp + negSum[g] / fn + (klSum[g] / fb) / fb;
    }
#pragma unroll
    for (int o = 1; o < 64; o <<= 1) lg += __shfl_xor(lg, o, 64);
    if ((threadIdx.x & 63u) == 0) atomicAdd(tot, lg);
}

__global__ void out_kernel(const float* __restrict__ tot, float* __restrict__ out,
                           int E, int G) {
    if (threadIdx.x == 0 && blockIdx.x == 0) {
        out[0] = tot[0] / (float)G;
        out[1] = 0.5f * (tot[1] / (float)E + tot[2] / (float)E);
    }
}

extern "C" void kernel_launch(void* const* d_in, const int* in_sizes, int n_in,
                              void* d_out, int out_size, void* d_ws, size_t ws_size,
                              hipStream_t stream) {
    const float* x    = (const float*)d_in[0];
    const float* attr = (const float*)d_in[1];
    const float* xm   = (const float*)d_in[2];
    const float* xsd  = (const float*)d_in[3];
    const float* W1   = (const float*)d_in[4];
    const float* b1   = (const float*)d_in[5];
    const float* W2   = (const float*)d_in[6];
    const float* b2   = (const float*)d_in[7];
    const float* We1  = (const float*)d_in[8];
    const float* be1  = (const float*)d_in[9];
    const float* We2  = (const float*)d_in[10];
    const float* be2  = (const float*)d_in[11];
    const int* ei     = (const int*)d_in[12];
    const int* ein    = (const int*)d_in[13];
    const int* eib    = (const int*)d_in[14];
    const int* einb   = (const int*)d_in[15];
    const int* batch  = (const int*)d_in[16];

    const int N = in_sizes[0] / D;       // 100000
    const int E = in_sizes[14];          // 600000
    const int G = 1024;

    float* ws = (float*)d_ws;
    float* posSum = ws;                  // [G]
    float* negSum = ws + G;              // [G]
    float* klSum  = ws + 2 * G;          // [G]
    float* tot    = ws + 3 * G;          // [0]=loss, [1]=sum lep, [2]=sum len

    hipMemsetAsync(d_ws, 0, (size_t)(3 * G + 3) * sizeof(float), stream);

    const int ntiles = (E + 63) / 64;
    const int grid = ntiles < 512 ? ntiles : 512;   // ~2 blocks/CU at ~110 VGPR

    pos_kernel<<<grid, 512, 0, stream>>>(x, ei, eib, W1, b1, W2, b2,
                                         We1, be1, We2, be2, attr,
                                         posSum, tot + 1, E, ntiles);
    neg_kernel<<<grid, 512, 0, stream>>>(x, ein, einb, We1, be1, We2, be2,
                                         negSum, tot + 2, E, ntiles);
    kl_kernel<<<(N + 255) / 256, 256, 0, stream>>>(xm, xsd, batch, klSum, N);
    final_kernel<<<(G + 255) / 256, 256, 0, stream>>>(eib, einb, batch,
                                                      posSum, negSum, klSum, tot, E, N, G);
    out_kernel<<<1, 64, 0, stream>>>(tot, (float*)d_out, E, G);
}

// Round 7
// 753.655 us; speedup vs baseline: 1.0357x; 1.0357x over previous
//
#include <hip/hip_runtime.h>
#include <math.h>

#define D 128

typedef __bf16 bf16x8 __attribute__((ext_vector_type(8)));
typedef float f32x4 __attribute__((ext_vector_type(4)));

__device__ __forceinline__ unsigned short f2bf(float f) {
    unsigned u = __float_as_uint(f);
    return (unsigned short)((u + 0x7FFFu + ((u >> 16) & 1u)) >> 16);
}
__device__ __forceinline__ float bf2f(unsigned short h) {
    return __uint_as_float(((unsigned)h) << 16);
}
__device__ __forceinline__ bf16x8 pack8(const unsigned* v) {
    union { uint4 u; bf16x8 b; } c;
    c.u.x = v[0]; c.u.y = v[1]; c.u.z = v[2]; c.u.w = v[3];
    return c.b;
}
__device__ __forceinline__ unsigned pair_bf(float a, float b) {
    return (unsigned)f2bf(a) | ((unsigned)f2bf(b) << 16);
}

__device__ __forceinline__ int lbound(const int* __restrict__ a, int L, int v) {
    int lo = 0, hi = L;
    while (lo < hi) { int m = (lo + hi) >> 1; if (a[m] < v) lo = m + 1; else hi = m; }
    return lo;
}

// Wave-level segmented atomic accumulate; all 64 lanes of the wave converged.
__device__ __forceinline__ void seg_atomic(float* __restrict__ seg, int g, float v, bool valid) {
    float tv = valid ? v : 0.f;
    float s = tv;
#pragma unroll
    for (int o = 1; o < 64; o <<= 1) s += __shfl_xor(s, o, 64);
    unsigned long long vb = __ballot(valid);
    if (vb == 0ULL) return;
    int g0 = __shfl(g, __ffsll((unsigned long long)vb) - 1, 64);
    unsigned long long ub = __ballot((!valid) || (g == g0));
    const int lane = (int)(threadIdx.x & 63u);
    if (ub == ~0ULL) {
        if (lane == 0) atomicAdd(seg + g0, s);
    } else {
        if (valid) atomicAdd(seg + g, tv);
    }
}

__device__ __forceinline__ void wave_add(float* __restrict__ dst, float v) {
    float s = v;
#pragma unroll
    for (int o = 1; o < 64; o <<= 1) s += __shfl_xor(s, o, 64);
    if ((threadIdx.x & 63u) == 0) atomicAdd(dst, s);
}

// Positive-edge kernel: both heads, M=64 edges/tile, 8 waves.
// Waves 0-3: W1-head cols 32w..32w+32 (plain bf16).  Waves 4-7: We1-head (hi+lo bf16).
// Gather software-pipelined 2-deep (idx 2 tiles ahead, first half-rows 1 tile ahead,
// issued right after barrier G to land during the MFMA phase). launch_bounds(512,2)
// so the ~100-VGPR pipeline state stays in registers (R6's (512,4)+arrays spilled
// ~300 MB/dispatch to scratch: WRITE_SIZE 1.7->105 MB).
__global__ __launch_bounds__(512, 2)
void pos_kernel(const float* __restrict__ x,
                const int* __restrict__ ei, const int* __restrict__ ebatch,
                const float* __restrict__ W1, const float* __restrict__ b1,
                const float* __restrict__ W2, const float* __restrict__ b2,
                const float* __restrict__ We1, const float* __restrict__ be1,
                const float* __restrict__ We2, const float* __restrict__ be2,
                const float* __restrict__ attr,
                float* __restrict__ posSum, float* __restrict__ tot1,
                int E, int ntiles) {
    __shared__ float smem[9104];
    unsigned short* As  = (unsigned short*)smem;            // 1024 slots x 16 B (16 KB)
    unsigned short* Hbf = (unsigned short*)(smem + 4096);   // H1 relu'd: [64][136] bf16
    float* posP = smem + 8448;                              // [4][64] We-head partials
    float* b1s  = smem + 8704;
    float* be1s = smem + 8832;
    float* We2s = smem + 8960;
    float* b2s  = smem + 9088;
    float* be2s = smem + 9096;

    const int t   = (int)threadIdx.x;
    const int wv  = t >> 6;
    const int l   = t & 63;
    const int sub = l & 15;
    const int q   = l >> 4;
    const int e_  = t >> 3;          // gather edge 0..63
    const int ks  = t & 7;           // gather k-slice
    const int k0  = ks * 16;

    // ---- gather pipeline prologue
    int cS = 0, cD = 0, nS = 0, nD = 0;
    float4 P0s, P1s, P0d, P1d;
    {
        const int tile0 = (int)blockIdx.x;
        const int Ei0 = tile0 * 64 + e_;
        if (tile0 < ntiles && Ei0 < E) {
            cS = ei[Ei0]; cD = ei[E + Ei0];
            const float4* ps = (const float4*)(x + (size_t)cS * D + k0);
            const float4* pd = (const float4*)(x + (size_t)cD * D + k0);
            P0s = ps[0]; P1s = ps[1]; P0d = pd[0]; P1d = pd[1];
        }
        const int t1  = tile0 + (int)gridDim.x;
        const int Ei1 = t1 * 64 + e_;
        if (t1 < ntiles && Ei1 < E) { nS = ei[Ei1]; nD = ei[E + Ei1]; }
    }

    // ---- B fragments, direct per-lane loads from global (one-time; W is L2-hot)
    bf16x8 Bh[2][4];   // wv<4: W1 cols; wv>=4: We1-hi cols
    bf16x8 Bl[2][4];   // wv>=4: We1-lo; wv<4: Bl[0][kt] = W2 fragment (layer-2 GEMM)
    {
        const float* Wsrc = (wv < 4) ? W1 : We1;
        const int jb = (wv & 3) * 32;
#pragma unroll
        for (int ct = 0; ct < 2; ct++) {
#pragma unroll
            for (int kt = 0; kt < 4; kt++) {
                unsigned vh[4], vl[4];
#pragma unroll
                for (int jj = 0; jj < 4; jj++) {
                    const float f0 = Wsrc[(kt * 32 + q * 8 + 2 * jj)     * D + jb + ct * 16 + sub];
                    const float f1 = Wsrc[(kt * 32 + q * 8 + 2 * jj + 1) * D + jb + ct * 16 + sub];
                    const unsigned short h0 = f2bf(f0), h1 = f2bf(f1);
                    vh[jj] = (unsigned)h0 | ((unsigned)h1 << 16);
                    const unsigned short g0 = f2bf(f0 - bf2f(h0));
                    const unsigned short g1 = f2bf(f1 - bf2f(h1));
                    vl[jj] = (unsigned)g0 | ((unsigned)g1 << 16);
                }
                Bh[ct][kt] = pack8(vh);
                if (wv >= 4) Bl[ct][kt] = pack8(vl);
            }
        }
        if (wv < 4) {   // W2 frags (B-operand of layer-2 GEMM), cols 7..15 zero
#pragma unroll
            for (int kt = 0; kt < 4; kt++) {
                const int kb = kt * 32 + q * 8;
                unsigned v[4];
#pragma unroll
                for (int jj = 0; jj < 4; jj++) {
                    unsigned short h0 = (sub < 7) ? f2bf(W2[(kb + 2 * jj) * 7 + sub]) : (unsigned short)0;
                    unsigned short h1 = (sub < 7) ? f2bf(W2[(kb + 2 * jj + 1) * 7 + sub]) : (unsigned short)0;
                    v[jj] = (unsigned)h0 | ((unsigned)h1 << 16);
                }
                Bl[0][kt] = pack8(v);
            }
        }
    }
    if (t < 128) { b1s[t] = b1[t]; be1s[t] = be1[t]; We2s[t] = We2[t]; }
    if (t < 7) b2s[t] = b2[t];
    if (t == 7) be2s[0] = be2[0];
    __syncthreads();

    float lpAcc = 0.f;

    for (int tile = (int)blockIdx.x; tile < ntiles; tile += (int)gridDim.x) {
        const int base = tile * 64;
        // ---- convert prefetched gather -> bf16 -> swizzled A frags (no local arrays)
        {
            const int Ei = base + e_;
            unsigned v0 = 0, v1 = 0, v2 = 0, v3 = 0, v4 = 0, v5 = 0, v6 = 0, v7 = 0;
            if (Ei < E) {
                const float4* ps = (const float4*)(x + (size_t)cS * D + k0);
                const float4* pd = (const float4*)(x + (size_t)cD * D + k0);
                const float4 S2 = ps[2], S3 = ps[3];      // same 128B line as P0s/P1s
                const float4 D2 = pd[2], D3 = pd[3];
                v0 = pair_bf(fmaxf(P0s.x * P0d.x, 0.f), fmaxf(P0s.y * P0d.y, 0.f));
                v1 = pair_bf(fmaxf(P0s.z * P0d.z, 0.f), fmaxf(P0s.w * P0d.w, 0.f));
                v2 = pair_bf(fmaxf(P1s.x * P1d.x, 0.f), fmaxf(P1s.y * P1d.y, 0.f));
                v3 = pair_bf(fmaxf(P1s.z * P1d.z, 0.f), fmaxf(P1s.w * P1d.w, 0.f));
                v4 = pair_bf(fmaxf(S2.x * D2.x, 0.f),   fmaxf(S2.y * D2.y, 0.f));
                v5 = pair_bf(fmaxf(S2.z * D2.z, 0.f),   fmaxf(S2.w * D2.w, 0.f));
                v6 = pair_bf(fmaxf(S3.x * D3.x, 0.f),   fmaxf(S3.y * D3.y, 0.f));
                v7 = pair_bf(fmaxf(S3.z * D3.z, 0.f),   fmaxf(S3.w * D3.w, 0.f));
            }
            const int slot = ((e_ >> 4) * 4 + (ks >> 1)) * 64 + (ks & 1) * 32 + (e_ & 15);
            uint4 u0; u0.x = v0; u0.y = v1; u0.z = v2; u0.w = v3;
            uint4 u1; u1.x = v4; u1.y = v5; u1.z = v6; u1.w = v7;
            *(uint4*)(As + slot * 8) = u0;
            *(uint4*)(As + (slot + 16) * 8) = u1;
        }
        __syncthreads();                    // barrier G
        // ---- prefetch: rows for tile+grid (idx already in regs), idx for tile+2*grid
        {
            const int nt  = tile + (int)gridDim.x;
            const int EiN = nt * 64 + e_;
            if (nt < ntiles && EiN < E) {
                cS = nS; cD = nD;
                const float4* ps = (const float4*)(x + (size_t)cS * D + k0);
                const float4* pd = (const float4*)(x + (size_t)cD * D + k0);
                P0s = ps[0]; P1s = ps[1]; P0d = pd[0]; P1d = pd[1];
            }
            const int nt2 = tile + 2 * (int)gridDim.x;
            const int Ei2 = nt2 * 64 + e_;
            if (nt2 < ntiles && Ei2 < E) { nS = ei[Ei2]; nD = ei[E + Ei2]; }
        }
        // ---- layer-1 MFMAs + per-wave epilogue
#pragma unroll
        for (int mt = 0; mt < 4; mt++) {
            bf16x8 a0 = *(const bf16x8*)(As + ((mt * 4 + 0) * 64 + l) * 8);
            bf16x8 a1 = *(const bf16x8*)(As + ((mt * 4 + 1) * 64 + l) * 8);
            bf16x8 a2 = *(const bf16x8*)(As + ((mt * 4 + 2) * 64 + l) * 8);
            bf16x8 a3 = *(const bf16x8*)(As + ((mt * 4 + 3) * 64 + l) * 8);
            float zp0 = 0.f, zp1 = 0.f, zp2 = 0.f, zp3 = 0.f;
#pragma unroll
            for (int ct = 0; ct < 2; ct++) {
                f32x4 c = {0.f, 0.f, 0.f, 0.f};
                c = __builtin_amdgcn_mfma_f32_16x16x32_bf16(a0, Bh[ct][0], c, 0, 0, 0);
                c = __builtin_amdgcn_mfma_f32_16x16x32_bf16(a1, Bh[ct][1], c, 0, 0, 0);
                c = __builtin_amdgcn_mfma_f32_16x16x32_bf16(a2, Bh[ct][2], c, 0, 0, 0);
                c = __builtin_amdgcn_mfma_f32_16x16x32_bf16(a3, Bh[ct][3], c, 0, 0, 0);
                if (wv >= 4) {
                    c = __builtin_amdgcn_mfma_f32_16x16x32_bf16(a0, Bl[ct][0], c, 0, 0, 0);
                    c = __builtin_amdgcn_mfma_f32_16x16x32_bf16(a1, Bl[ct][1], c, 0, 0, 0);
                    c = __builtin_amdgcn_mfma_f32_16x16x32_bf16(a2, Bl[ct][2], c, 0, 0, 0);
                    c = __builtin_amdgcn_mfma_f32_16x16x32_bf16(a3, Bl[ct][3], c, 0, 0, 0);
                }
                const int jloc = (wv & 3) * 32 + ct * 16 + sub;
                if (wv < 4) {
                    const float bb = b1s[jloc];
#pragma unroll
                    for (int r = 0; r < 4; r++)
                        Hbf[(mt * 16 + q * 4 + r) * 136 + jloc] = f2bf(fmaxf(c[r] + bb, 0.f));
                } else {
                    const float bb = be1s[jloc], ww = We2s[jloc];
                    zp0 += fmaxf(c[0] + bb, 0.f) * ww;
                    zp1 += fmaxf(c[1] + bb, 0.f) * ww;
                    zp2 += fmaxf(c[2] + bb, 0.f) * ww;
                    zp3 += fmaxf(c[3] + bb, 0.f) * ww;
                }
            }
            if (wv >= 4) {
#pragma unroll
                for (int o = 1; o < 16; o <<= 1) {
                    zp0 += __shfl_xor(zp0, o, 64);
                    zp1 += __shfl_xor(zp1, o, 64);
                    zp2 += __shfl_xor(zp2, o, 64);
                    zp3 += __shfl_xor(zp3, o, 64);
                }
                if (sub < 4) {
                    float vv = (sub == 0) ? zp0 : (sub == 1) ? zp1 : (sub == 2) ? zp2 : zp3;
                    posP[(wv - 4) * 64 + mt * 16 + q * 4 + sub] = vv;
                }
            }
        }
        __syncthreads();                    // barrier M
        // ---- layer 2 (waves 0-3): S = Hbf @ W2frag via MFMA; lane sub==7 does We-head
        if (wv < 4) {
            f32x4 cS2 = {0.f, 0.f, 0.f, 0.f};
#pragma unroll
            for (int jt = 0; jt < 4; jt++) {
                bf16x8 hf = *(const bf16x8*)(Hbf + (wv * 16 + sub) * 136 + jt * 32 + q * 8);
                cS2 = __builtin_amdgcn_mfma_f32_16x16x32_bf16(hf, Bl[0][jt], cS2, 0, 0, 0);
            }
            float bceP[4] = {0.f, 0.f, 0.f, 0.f};
            float lpP[4]  = {0.f, 0.f, 0.f, 0.f};
#pragma unroll
            for (int r = 0; r < 4; r++) {
                const int e = wv * 16 + q * 4 + r;
                const int Ei = base + e;
                const bool vE = (Ei < E);
                if (sub < 7 && vE) {
                    const float z = cS2[r] + b2s[sub];
                    const float p = 1.f / (1.f + expf(-z));
                    const float ta = attr[(size_t)Ei * 9 + sub];
                    bceP[r] = -(ta * fmaxf(logf(p), -100.f)
                              + (1.f - ta) * fmaxf(log1pf(-p), -100.f));
                } else if (sub == 7 && vE) {
                    const float zp = posP[e] + posP[64 + e] + posP[128 + e] + posP[192 + e] + be2s[0];
                    const float pp = 1.f / (1.f + expf(-zp));
                    lpP[r]  = -fmaxf(logf(pp), -100.f);
                    bceP[r] = lpP[r];
                }
            }
#pragma unroll
            for (int o = 1; o < 16; o <<= 1)
#pragma unroll
                for (int r = 0; r < 4; r++) {
                    bceP[r] += __shfl_xor(bceP[r], o, 64);
                    lpP[r]  += __shfl_xor(lpP[r],  o, 64);
                }
            const float lossSel = (sub == 0) ? bceP[0] : (sub == 1) ? bceP[1]
                                : (sub == 2) ? bceP[2] : bceP[3];
            const float lpSel   = (sub == 0) ? lpP[0] : (sub == 1) ? lpP[1]
                                : (sub == 2) ? lpP[2] : lpP[3];
            const int eW  = wv * 16 + q * 4 + (sub & 3);
            const int EiW = base + eW;
            const bool act = (sub < 4) && (EiW < E);
            const int g = ebatch[EiW < E ? EiW : E - 1];
            seg_atomic(posSum, g, lossSel, act);
            lpAcc += act ? lpSel : 0.f;
        }
    }
    if (wv < 4) wave_add(tot1, lpAcc);
}

// Negative-edge kernel: We-head only. M=64, 8 waves x 16 cols, We1 hi+lo.
__global__ __launch_bounds__(512, 2)
void neg_kernel(const float* __restrict__ x,
                const int* __restrict__ ei, const int* __restrict__ ebatch,
                const float* __restrict__ We1, const float* __restrict__ be1,
                const float* __restrict__ We2, const float* __restrict__ be2,
                float* __restrict__ negSum, float* __restrict__ tot2,
                int E, int ntiles) {
    __shared__ float smem[4872];
    unsigned short* As = (unsigned short*)smem;     // 16 KB A frags
    float* negP = smem + 4096;                      // [8][64]
    float* be1s = smem + 4608;
    float* We2s = smem + 4736;
    float* be2s = smem + 4864;

    const int t   = (int)threadIdx.x;
    const int wv  = t >> 6;
    const int l   = t & 63;
    const int sub = l & 15;
    const int q   = l >> 4;
    const int e_  = t >> 3;
    const int ks  = t & 7;
    const int k0  = ks * 16;

    // ---- gather pipeline prologue
    int cS = 0, cD = 0, nS = 0, nD = 0;
    float4 P0s, P1s, P0d, P1d;
    {
        const int tile0 = (int)blockIdx.x;
        const int Ei0 = tile0 * 64 + e_;
        if (tile0 < ntiles && Ei0 < E) {
            cS = ei[Ei0]; cD = ei[E + Ei0];
            const float4* ps = (const float4*)(x + (size_t)cS * D + k0);
            const float4* pd = (const float4*)(x + (size_t)cD * D + k0);
            P0s = ps[0]; P1s = ps[1]; P0d = pd[0]; P1d = pd[1];
        }
        const int t1  = tile0 + (int)gridDim.x;
        const int Ei1 = t1 * 64 + e_;
        if (t1 < ntiles && Ei1 < E) { nS = ei[Ei1]; nD = ei[E + Ei1]; }
    }

    // ---- B fragments, direct per-lane loads
    bf16x8 Bh[4], Bl[4];
    {
        const int jb = wv * 16;
#pragma unroll
        for (int kt = 0; kt < 4; kt++) {
            unsigned vh[4], vl[4];
#pragma unroll
            for (int jj = 0; jj < 4; jj++) {
                const float f0 = We1[(kt * 32 + q * 8 + 2 * jj)     * D + jb + sub];
                const float f1 = We1[(kt * 32 + q * 8 + 2 * jj + 1) * D + jb + sub];
                const unsigned short h0 = f2bf(f0), h1 = f2bf(f1);
                vh[jj] = (unsigned)h0 | ((unsigned)h1 << 16);
                const unsigned short g0 = f2bf(f0 - bf2f(h0));
                const unsigned short g1 = f2bf(f1 - bf2f(h1));
                vl[jj] = (unsigned)g0 | ((unsigned)g1 << 16);
            }
            Bh[kt] = pack8(vh);
            Bl[kt] = pack8(vl);
        }
    }
    if (t < 128) { be1s[t] = be1[t]; We2s[t] = We2[t]; }
    if (t == 128) be2s[0] = be2[0];
    __syncthreads();

    float lnAcc = 0.f;

    for (int tile = (int)blockIdx.x; tile < ntiles; tile += (int)gridDim.x) {
        const int base = tile * 64;
        {
            const int Ei = base + e_;
            unsigned v0 = 0, v1 = 0, v2 = 0, v3 = 0, v4 = 0, v5 = 0, v6 = 0, v7 = 0;
            if (Ei < E) {
                const float4* ps = (const float4*)(x + (size_t)cS * D + k0);
                const float4* pd = (const float4*)(x + (size_t)cD * D + k0);
                const float4 S2 = ps[2], S3 = ps[3];
                const float4 D2 = pd[2], D3 = pd[3];
                v0 = pair_bf(fmaxf(P0s.x * P0d.x, 0.f), fmaxf(P0s.y * P0d.y, 0.f));
                v1 = pair_bf(fmaxf(P0s.z * P0d.z, 0.f), fmaxf(P0s.w * P0d.w, 0.f));
                v2 = pair_bf(fmaxf(P1s.x * P1d.x, 0.f), fmaxf(P1s.y * P1d.y, 0.f));
                v3 = pair_bf(fmaxf(P1s.z * P1d.z, 0.f), fmaxf(P1s.w * P1d.w, 0.f));
                v4 = pair_bf(fmaxf(S2.x * D2.x, 0.f),   fmaxf(S2.y * D2.y, 0.f));
                v5 = pair_bf(fmaxf(S2.z * D2.z, 0.f),   fmaxf(S2.w * D2.w, 0.f));
                v6 = pair_bf(fmaxf(S3.x * D3.x, 0.f),   fmaxf(S3.y * D3.y, 0.f));
                v7 = pair_bf(fmaxf(S3.z * D3.z, 0.f),   fmaxf(S3.w * D3.w, 0.f));
            }
            const int slot = ((e_ >> 4) * 4 + (ks >> 1)) * 64 + (ks & 1) * 32 + (e_ & 15);
            uint4 u0; u0.x = v0; u0.y = v1; u0.z = v2; u0.w = v3;
            uint4 u1; u1.x = v4; u1.y = v5; u1.z = v6; u1.w = v7;
            *(uint4*)(As + slot * 8) = u0;
            *(uint4*)(As + (slot + 16) * 8) = u1;
        }
        __syncthreads();
        {
            const int nt  = tile + (int)gridDim.x;
            const int EiN = nt * 64 + e_;
            if (nt < ntiles && EiN < E) {
                cS = nS; cD = nD;
                const float4* ps = (const float4*)(x + (size_t)cS * D + k0);
                const float4* pd = (const float4*)(x + (size_t)cD * D + k0);
                P0s = ps[0]; P1s = ps[1]; P0d = pd[0]; P1d = pd[1];
            }
            const int nt2 = tile + 2 * (int)gridDim.x;
            const int Ei2 = nt2 * 64 + e_;
            if (nt2 < ntiles && Ei2 < E) { nS = ei[Ei2]; nD = ei[E + Ei2]; }
        }
        const int j = wv * 16 + sub;
        const float bb = be1s[j], ww = We2s[j];
#pragma unroll
        for (int mt = 0; mt < 4; mt++) {
            bf16x8 a0 = *(const bf16x8*)(As + ((mt * 4 + 0) * 64 + l) * 8);
            bf16x8 a1 = *(const bf16x8*)(As + ((mt * 4 + 1) * 64 + l) * 8);
            bf16x8 a2 = *(const bf16x8*)(As + ((mt * 4 + 2) * 64 + l) * 8);
            bf16x8 a3 = *(const bf16x8*)(As + ((mt * 4 + 3) * 64 + l) * 8);
            f32x4 c = {0.f, 0.f, 0.f, 0.f};
            c = __builtin_amdgcn_mfma_f32_16x16x32_bf16(a0, Bh[0], c, 0, 0, 0);
            c = __builtin_amdgcn_mfma_f32_16x16x32_bf16(a1, Bh[1], c, 0, 0, 0);
            c = __builtin_amdgcn_mfma_f32_16x16x32_bf16(a2, Bh[2], c, 0, 0, 0);
            c = __builtin_amdgcn_mfma_f32_16x16x32_bf16(a3, Bh[3], c, 0, 0, 0);
            c = __builtin_amdgcn_mfma_f32_16x16x32_bf16(a0, Bl[0], c, 0, 0, 0);
            c = __builtin_amdgcn_mfma_f32_16x16x32_bf16(a1, Bl[1], c, 0, 0, 0);
            c = __builtin_amdgcn_mfma_f32_16x16x32_bf16(a2, Bl[2], c, 0, 0, 0);
            c = __builtin_amdgcn_mfma_f32_16x16x32_bf16(a3, Bl[3], c, 0, 0, 0);
            float zp0 = fmaxf(c[0] + bb, 0.f) * ww;
            float zp1 = fmaxf(c[1] + bb, 0.f) * ww;
            float zp2 = fmaxf(c[2] + bb, 0.f) * ww;
            float zp3 = fmaxf(c[3] + bb, 0.f) * ww;
#pragma unroll
            for (int o = 1; o < 16; o <<= 1) {
                zp0 += __shfl_xor(zp0, o, 64);
                zp1 += __shfl_xor(zp1, o, 64);
                zp2 += __shfl_xor(zp2, o, 64);
                zp3 += __shfl_xor(zp3, o, 64);
            }
            if (sub < 4) {
                float vv = (sub == 0) ? zp0 : (sub == 1) ? zp1 : (sub == 2) ? zp2 : zp3;
                negP[wv * 64 + mt * 16 + q * 4 + sub] = vv;
            }
        }
        __syncthreads();
        if (wv == 0) {
            const int Ei = base + l;
            const bool valid = (Ei < E);
            float zp = be2s[0];
#pragma unroll
            for (int i = 0; i < 8; i++) zp += negP[i * 64 + l];
            float lossN = 0.f;
            if (valid) {
                const float pp = 1.f / (1.f + expf(-zp));
                lossN = -fmaxf(log1pf(-pp), -100.f);
            }
            const int g = ebatch[Ei < E ? Ei : E - 1];
            seg_atomic(negSum, g, lossN, valid);
            lnAcc += valid ? lossN : 0.f;
        }
    }
    if (wv == 0) wave_add(tot2, lnAcc);
}

__global__ __launch_bounds__(256)
void kl_kernel(const float* __restrict__ xm, const float* __restrict__ xs,
               const int* __restrict__ batch, float* __restrict__ klSum, int N) {
    const int n = (int)(blockIdx.x * 256 + threadIdx.x);
    const bool valid = (n < N);
    float kl = 0.f;
    int g = 0;
    if (valid) {
        const float4* m4 = (const float4*)(xm + (size_t)n * D);
        const float4* s4 = (const float4*)(xs + (size_t)n * D);
        float s = 0.f;
        // Clamp log at -1e4 (< log(min denormal)): bit-identical for sd > 0,
        // finite at sd == 0 where the reference is +inf (threshold inf).
#pragma unroll 8
        for (int i = 0; i < 32; i++) {
            const float4 m = m4[i];
            const float4 sd = s4[i];
            s += 1.f + 2.f * fmaxf(logf(sd.x), -1e4f) - m.x * m.x - sd.x * sd.x;
            s += 1.f + 2.f * fmaxf(logf(sd.y), -1e4f) - m.y * m.y - sd.y * sd.y;
            s += 1.f + 2.f * fmaxf(logf(sd.z), -1e4f) - m.z * m.z - sd.z * sd.z;
            s += 1.f + 2.f * fmaxf(logf(sd.w), -1e4f) - m.w * m.w - sd.w * sd.w;
        }
        kl = -0.5f * s;
        g = batch[n];
    }
    seg_atomic(klSum, g, kl, valid);
}

__global__ __launch_bounds__(256)
void final_kernel(const int* __restrict__ eib, const int* __restrict__ einb,
                  const int* __restrict__ nbatch,
                  const float* __restrict__ posSum, const float* __restrict__ negSum,
                  const float* __restrict__ klSum,
                  float* __restrict__ tot, int E, int N, int G) {
    const int g = (int)(blockIdx.x * blockDim.x + threadIdx.x);
    float lg = 0.f;
    if (g < G) {
        const int cP = lbound(eib, E, g + 1) - lbound(eib, E, g);
        const int cN = lbound(einb, E, g + 1) - lbound(einb, E, g);
        const int cB = lbound(nbatch, N, g + 1) - lbound(nbatch, N, g);
        const float fp = fmaxf((float)cP, 1.f);
        const float fn = fmaxf((float)cN, 1.f);
        const float fb = fmaxf((float)cB, 1.f);
        lg = posSum[g] / fp + negSum[g] / fn + (klSum[g] / fb) / fb;
    }
#pragma unroll
    for (int o = 1; o < 64; o <<= 1) lg += __shfl_xor(lg, o, 64);
    if ((threadIdx.x & 63u) == 0) atomicAdd(tot, lg);
}

__global__ void out_kernel(const float* __restrict__ tot, float* __restrict__ out,
                           int E, int G) {
    if (threadIdx.x == 0 && blockIdx.x == 0) {
        out[0] = tot[0] / (float)G;
        out[1] = 0.5f * (tot[1] / (float)E + tot[2] / (float)E);
    }
}

extern "C" void kernel_launch(void* const* d_in, const int* in_sizes, int n_in,
                              void* d_out, int out_size, void* d_ws, size_t ws_size,
                              hipStream_t stream) {
    const float* x    = (const float*)d_in[0];
    const float* attr = (const float*)d_in[1];
    const float* xm   = (const float*)d_in[2];
    const float* xsd  = (const float*)d_in[3];
    const float* W1   = (const float*)d_in[4];
    const float* b1   = (const float*)d_in[5];
    const float* W2   = (const float*)d_in[6];
    const float* b2   = (const float*)d_in[7];
    const float* We1  = (const float*)d_in[8];
    const float* be1  = (const float*)d_in[9];
    const float* We2  = (const float*)d_in[10];
    const float* be2  = (const float*)d_in[11];
    const int* ei     = (const int*)d_in[12];
    const int* ein    = (const int*)d_in[13];
    const int* eib    = (const int*)d_in[14];
    const int* einb   = (const int*)d_in[15];
    const int* batch  = (const int*)d_in[16];

    const int N = in_sizes[0] / D;       // 100000
    const int E = in_sizes[14];          // 600000
    const int G = 1024;

    float* ws = (float*)d_ws;
    float* posSum = ws;                  // [G]
    float* negSum = ws + G;              // [G]
    float* klSum  = ws + 2 * G;          // [G]
    float* tot    = ws + 3 * G;          // [0]=loss, [1]=sum lep, [2]=sum len

    hipMemsetAsync(d_ws, 0, (size_t)(3 * G + 3) * sizeof(float), stream);

    const int ntiles = (E + 63) / 64;
    const int grid = ntiles < 1024 ? ntiles : 1024;

    pos_kernel<<<grid, 512, 0, stream>>>(x, ei, eib, W1, b1, W2, b2,
                                         We1, be1, We2, be2, attr,
                                         posSum, tot + 1, E, ntiles);
    neg_kernel<<<grid, 512, 0, stream>>>(x, ein, einb, We1, be1, We2, be2,
                                         negSum, tot + 2, E, ntiles);
    kl_kernel<<<(N + 255) / 256, 256, 0, stream>>>(xm, xsd, batch, klSum, N);
    final_kernel<<<(G + 255) / 256, 256, 0, stream>>>(eib, einb, batch,
                                                      posSum, negSum, klSum, tot, E, N, G);
    out_kernel<<<1, 64, 0, stream>>>(tot, (float*)d_out, E, G);
}

// Round 8
// 693.934 us; speedup vs baseline: 1.1249x; 1.0861x over previous
//
#include <hip/hip_runtime.h>
#include <math.h>

#define D 128

typedef __bf16 bf16x8 __attribute__((ext_vector_type(8)));
typedef float f32x4 __attribute__((ext_vector_type(4)));

__device__ __forceinline__ unsigned short f2bf(float f) {
    unsigned u = __float_as_uint(f);
    return (unsigned short)((u + 0x7FFFu + ((u >> 16) & 1u)) >> 16);
}
__device__ __forceinline__ float bf2f(unsigned short h) {
    return __uint_as_float(((unsigned)h) << 16);
}
__device__ __forceinline__ bf16x8 pack8(const unsigned* v) {
    union { uint4 u; bf16x8 b; } c;
    c.u.x = v[0]; c.u.y = v[1]; c.u.z = v[2]; c.u.w = v[3];
    return c.b;
}
__device__ __forceinline__ unsigned pair_bf(float a, float b) {
    return (unsigned)f2bf(a) | ((unsigned)f2bf(b) << 16);
}

__device__ __forceinline__ int lbound(const int* __restrict__ a, int L, int v) {
    int lo = 0, hi = L;
    while (lo < hi) { int m = (lo + hi) >> 1; if (a[m] < v) lo = m + 1; else hi = m; }
    return lo;
}

// Wave-level segmented atomic accumulate; all 64 lanes of the wave converged.
__device__ __forceinline__ void seg_atomic(float* __restrict__ seg, int g, float v, bool valid) {
    float tv = valid ? v : 0.f;
    float s = tv;
#pragma unroll
    for (int o = 1; o < 64; o <<= 1) s += __shfl_xor(s, o, 64);
    unsigned long long vb = __ballot(valid);
    if (vb == 0ULL) return;
    int g0 = __shfl(g, __ffsll((unsigned long long)vb) - 1, 64);
    unsigned long long ub = __ballot((!valid) || (g == g0));
    const int lane = (int)(threadIdx.x & 63u);
    if (ub == ~0ULL) {
        if (lane == 0) atomicAdd(seg + g0, s);
    } else {
        if (valid) atomicAdd(seg + g, tv);
    }
}

__device__ __forceinline__ void wave_add(float* __restrict__ dst, float v) {
    float s = v;
#pragma unroll
    for (int o = 1; o < 64; o <<= 1) s += __shfl_xor(s, o, 64);
    if ((threadIdx.x & 63u) == 0) atomicAdd(dst, s);
}

// Positive-edge kernel (R5 skeleton, shuffle-trees removed).
// Waves 0-3: W1-head cols 32w..+32 -> Hbf (bf16).  Waves 4-7: We1-head hi+lo -> He (bf16).
// Layer 2 is pure MFMA: waves 0-3 Hbf@W2 (BCE cols), waves 4-7 He@[We2hi,We2lo].
// One collector wave sums losses from LDS: one seg_atomic per tile, zero per-mt trees.
__global__ __launch_bounds__(512, 4)
void pos_kernel(const float* __restrict__ x,
                const int* __restrict__ ei, const int* __restrict__ ebatch,
                const float* __restrict__ W1, const float* __restrict__ b1,
                const float* __restrict__ W2, const float* __restrict__ b2,
                const float* __restrict__ We1, const float* __restrict__ be1,
                const float* __restrict__ We2, const float* __restrict__ be2,
                const float* __restrict__ attr,
                float* __restrict__ posSum, float* __restrict__ tot1,
                int E, int ntiles) {
    __shared__ float smem[13768];
    unsigned short* As  = (unsigned short*)smem;           // 1024 slots x 16 B
    unsigned short* Hbf = (unsigned short*)(smem + 4096);  // attr H: [64][136] bf16
    unsigned short* He  = (unsigned short*)(smem + 8448);  // We-head H: [64][136] bf16
    float* bceL = smem + 12800;                            // [64][9]
    float* zL   = smem + 13376;                            // [2][64]
    float* b1s  = smem + 13504;
    float* be1s = smem + 13632;
    float* b2s  = smem + 13760;                            // 7
    float* be2s = smem + 13767;                            // 1

    const int t   = (int)threadIdx.x;
    const int wv  = t >> 6;
    const int l   = t & 63;
    const int sub = l & 15;
    const int q   = l >> 4;
    const int e_  = t >> 3;          // gather edge 0..63
    const int ks  = t & 7;           // gather k-slice
    const int k0  = ks * 16;

    // ---- B fragments (one-time; W is L2-hot)
    bf16x8 Bh[2][4];   // wv<4: W1 cols; wv>=4: We1-hi cols
    bf16x8 Bl[2][4];   // wv>=4: We1-lo
    bf16x8 Bc2[4];     // wv<4: W2 cols (7 used); wv>=4: [We2hi | We2lo | 0...]
    {
        const float* Wsrc = (wv < 4) ? W1 : We1;
        const int jb = (wv & 3) * 32;
#pragma unroll
        for (int ct = 0; ct < 2; ct++) {
#pragma unroll
            for (int kt = 0; kt < 4; kt++) {
                unsigned vh[4], vl[4];
#pragma unroll
                for (int jj = 0; jj < 4; jj++) {
                    const float f0 = Wsrc[(kt * 32 + q * 8 + 2 * jj)     * D + jb + ct * 16 + sub];
                    const float f1 = Wsrc[(kt * 32 + q * 8 + 2 * jj + 1) * D + jb + ct * 16 + sub];
                    const unsigned short h0 = f2bf(f0), h1 = f2bf(f1);
                    vh[jj] = (unsigned)h0 | ((unsigned)h1 << 16);
                    const unsigned short g0 = f2bf(f0 - bf2f(h0));
                    const unsigned short g1 = f2bf(f1 - bf2f(h1));
                    vl[jj] = (unsigned)g0 | ((unsigned)g1 << 16);
                }
                Bh[ct][kt] = pack8(vh);
                if (wv >= 4) Bl[ct][kt] = pack8(vl);
            }
        }
#pragma unroll
        for (int kt = 0; kt < 4; kt++) {
            const int kb = kt * 32 + q * 8;
            unsigned v[4];
#pragma unroll
            for (int jj = 0; jj < 4; jj++) {
                unsigned short h0 = 0, h1 = 0;
                if (wv < 4) {
                    if (sub < 7) {
                        h0 = f2bf(W2[(kb + 2 * jj) * 7 + sub]);
                        h1 = f2bf(W2[(kb + 2 * jj + 1) * 7 + sub]);
                    }
                } else {
                    const float f0 = We2[kb + 2 * jj];
                    const float f1 = We2[kb + 2 * jj + 1];
                    if (sub == 0) { h0 = f2bf(f0); h1 = f2bf(f1); }
                    else if (sub == 1) {
                        h0 = f2bf(f0 - bf2f(f2bf(f0)));
                        h1 = f2bf(f1 - bf2f(f2bf(f1)));
                    }
                }
                v[jj] = (unsigned)h0 | ((unsigned)h1 << 16);
            }
            Bc2[kt] = pack8(v);
        }
    }
    if (t < 128) { b1s[t] = b1[t]; be1s[t] = be1[t]; }
    if (t < 7) b2s[t] = b2[t];
    if (t == 7) be2s[0] = be2[0];
    __syncthreads();

    float lpAcc = 0.f;

    for (int tile = (int)blockIdx.x; tile < ntiles; tile += (int)gridDim.x) {
        const int base = tile * 64;
        // ---- gather em = relu(x[s]*x[d]) -> bf16 -> swizzled A frags
        {
            const int Ei = base + e_;
            unsigned v0 = 0, v1 = 0, v2 = 0, v3 = 0, v4 = 0, v5 = 0, v6 = 0, v7 = 0;
            if (Ei < E) {
                const int s0 = ei[Ei], d0 = ei[E + Ei];
                const float4* ps = (const float4*)(x + (size_t)s0 * D + k0);
                const float4* pd = (const float4*)(x + (size_t)d0 * D + k0);
                const float4 S0 = ps[0], S1 = ps[1], S2 = ps[2], S3 = ps[3];
                const float4 D0 = pd[0], D1 = pd[1], D2 = pd[2], D3 = pd[3];
                v0 = pair_bf(fmaxf(S0.x * D0.x, 0.f), fmaxf(S0.y * D0.y, 0.f));
                v1 = pair_bf(fmaxf(S0.z * D0.z, 0.f), fmaxf(S0.w * D0.w, 0.f));
                v2 = pair_bf(fmaxf(S1.x * D1.x, 0.f), fmaxf(S1.y * D1.y, 0.f));
                v3 = pair_bf(fmaxf(S1.z * D1.z, 0.f), fmaxf(S1.w * D1.w, 0.f));
                v4 = pair_bf(fmaxf(S2.x * D2.x, 0.f), fmaxf(S2.y * D2.y, 0.f));
                v5 = pair_bf(fmaxf(S2.z * D2.z, 0.f), fmaxf(S2.w * D2.w, 0.f));
                v6 = pair_bf(fmaxf(S3.x * D3.x, 0.f), fmaxf(S3.y * D3.y, 0.f));
                v7 = pair_bf(fmaxf(S3.z * D3.z, 0.f), fmaxf(S3.w * D3.w, 0.f));
            }
            const int slot = ((e_ >> 4) * 4 + (ks >> 1)) * 64 + (ks & 1) * 32 + (e_ & 15);
            uint4 u0; u0.x = v0; u0.y = v1; u0.z = v2; u0.w = v3;
            uint4 u1; u1.x = v4; u1.y = v5; u1.z = v6; u1.w = v7;
            *(uint4*)(As + slot * 8) = u0;
            *(uint4*)(As + (slot + 16) * 8) = u1;
        }
        __syncthreads();                    // barrier G
        // ---- layer-1 MFMAs; H tiles to LDS (bf16), NO shuffle trees
#pragma unroll
        for (int mt = 0; mt < 4; mt++) {
            bf16x8 a0 = *(const bf16x8*)(As + ((mt * 4 + 0) * 64 + l) * 8);
            bf16x8 a1 = *(const bf16x8*)(As + ((mt * 4 + 1) * 64 + l) * 8);
            bf16x8 a2 = *(const bf16x8*)(As + ((mt * 4 + 2) * 64 + l) * 8);
            bf16x8 a3 = *(const bf16x8*)(As + ((mt * 4 + 3) * 64 + l) * 8);
#pragma unroll
            for (int ct = 0; ct < 2; ct++) {
                f32x4 c = {0.f, 0.f, 0.f, 0.f};
                c = __builtin_amdgcn_mfma_f32_16x16x32_bf16(a0, Bh[ct][0], c, 0, 0, 0);
                c = __builtin_amdgcn_mfma_f32_16x16x32_bf16(a1, Bh[ct][1], c, 0, 0, 0);
                c = __builtin_amdgcn_mfma_f32_16x16x32_bf16(a2, Bh[ct][2], c, 0, 0, 0);
                c = __builtin_amdgcn_mfma_f32_16x16x32_bf16(a3, Bh[ct][3], c, 0, 0, 0);
                if (wv >= 4) {
                    c = __builtin_amdgcn_mfma_f32_16x16x32_bf16(a0, Bl[ct][0], c, 0, 0, 0);
                    c = __builtin_amdgcn_mfma_f32_16x16x32_bf16(a1, Bl[ct][1], c, 0, 0, 0);
                    c = __builtin_amdgcn_mfma_f32_16x16x32_bf16(a2, Bl[ct][2], c, 0, 0, 0);
                    c = __builtin_amdgcn_mfma_f32_16x16x32_bf16(a3, Bl[ct][3], c, 0, 0, 0);
                }
                const int jloc = (wv & 3) * 32 + ct * 16 + sub;
                if (wv < 4) {
                    const float bb = b1s[jloc];
#pragma unroll
                    for (int r = 0; r < 4; r++)
                        Hbf[(mt * 16 + q * 4 + r) * 136 + jloc] = f2bf(fmaxf(c[r] + bb, 0.f));
                } else {
                    const float bb = be1s[jloc];
#pragma unroll
                    for (int r = 0; r < 4; r++)
                        He[(mt * 16 + q * 4 + r) * 136 + jloc] = f2bf(fmaxf(c[r] + bb, 0.f));
                }
            }
        }
        __syncthreads();                    // barrier M
        // ---- layer 2: all waves, pure MFMA
        if (wv < 4) {
            f32x4 cS2 = {0.f, 0.f, 0.f, 0.f};
#pragma unroll
            for (int jt = 0; jt < 4; jt++) {
                bf16x8 hf = *(const bf16x8*)(Hbf + (wv * 16 + sub) * 136 + jt * 32 + q * 8);
                cS2 = __builtin_amdgcn_mfma_f32_16x16x32_bf16(hf, Bc2[jt], cS2, 0, 0, 0);
            }
            if (sub < 7) {
#pragma unroll
                for (int r = 0; r < 4; r++) {
                    const int e = wv * 16 + q * 4 + r;
                    const int Ei = base + e;
                    float bce = 0.f;
                    if (Ei < E) {
                        const float z = cS2[r] + b2s[sub];
                        const float p = 1.f / (1.f + expf(-z));
                        const float ta = attr[(size_t)Ei * 9 + sub];
                        bce = -(ta * fmaxf(logf(p), -100.f)
                              + (1.f - ta) * fmaxf(log1pf(-p), -100.f));
                    }
                    bceL[e * 9 + sub] = bce;
                }
            }
        } else {
            f32x4 cW = {0.f, 0.f, 0.f, 0.f};
#pragma unroll
            for (int jt = 0; jt < 4; jt++) {
                bf16x8 hf = *(const bf16x8*)(He + ((wv - 4) * 16 + sub) * 136 + jt * 32 + q * 8);
                cW = __builtin_amdgcn_mfma_f32_16x16x32_bf16(hf, Bc2[jt], cW, 0, 0, 0);
            }
            if (sub < 2) {
#pragma unroll
                for (int r = 0; r < 4; r++)
                    zL[sub * 64 + (wv - 4) * 16 + q * 4 + r] = cW[r];
            }
        }
        __syncthreads();                    // barrier L
        // ---- collector: wave 0, lane = edge; one seg_atomic per tile
        if (wv == 0) {
            const int Ei = base + l;
            const bool valid = (Ei < E);
            float loss = 0.f, lep = 0.f;
            if (valid) {
                float bsum = 0.f;
#pragma unroll
                for (int c = 0; c < 7; c++) bsum += bceL[l * 9 + c];
                const float z = zL[l] + zL[64 + l] + be2s[0];
                const float p = 1.f / (1.f + expf(-z));
                lep = -fmaxf(logf(p), -100.f);
                loss = bsum + lep;
            }
            const int g = ebatch[Ei < E ? Ei : E - 1];
            seg_atomic(posSum, g, loss, valid);
            lpAcc += valid ? lep : 0.f;
        }
    }
    if (wv == 0) wave_add(tot1, lpAcc);
}

// Negative-edge kernel: We-head only, same shuffle-free structure.
// l1: 8 waves x 16 cols (We1 hi+lo) -> He bf16.  l2: waves 0-3, He @ [We2hi|We2lo].
__global__ __launch_bounds__(512, 4)
void neg_kernel(const float* __restrict__ x,
                const int* __restrict__ ei, const int* __restrict__ ebatch,
                const float* __restrict__ We1, const float* __restrict__ be1,
                const float* __restrict__ We2, const float* __restrict__ be2,
                float* __restrict__ negSum, float* __restrict__ tot2,
                int E, int ntiles) {
    __shared__ float smem[8705];
    unsigned short* As = (unsigned short*)smem;            // 16 KB A frags
    unsigned short* He = (unsigned short*)(smem + 4096);   // [64][136] bf16
    float* zL   = smem + 8448;                             // [2][64]
    float* be1s = smem + 8576;
    float* be2s = smem + 8704;

    const int t   = (int)threadIdx.x;
    const int wv  = t >> 6;
    const int l   = t & 63;
    const int sub = l & 15;
    const int q   = l >> 4;
    const int e_  = t >> 3;
    const int ks  = t & 7;
    const int k0  = ks * 16;

    bf16x8 Bh[4], Bl[4], Bc2[4];
    {
        const int jb = wv * 16;
#pragma unroll
        for (int kt = 0; kt < 4; kt++) {
            unsigned vh[4], vl[4];
#pragma unroll
            for (int jj = 0; jj < 4; jj++) {
                const float f0 = We1[(kt * 32 + q * 8 + 2 * jj)     * D + jb + sub];
                const float f1 = We1[(kt * 32 + q * 8 + 2 * jj + 1) * D + jb + sub];
                const unsigned short h0 = f2bf(f0), h1 = f2bf(f1);
                vh[jj] = (unsigned)h0 | ((unsigned)h1 << 16);
                const unsigned short g0 = f2bf(f0 - bf2f(h0));
                const unsigned short g1 = f2bf(f1 - bf2f(h1));
                vl[jj] = (unsigned)g0 | ((unsigned)g1 << 16);
            }
            Bh[kt] = pack8(vh);
            Bl[kt] = pack8(vl);
        }
#pragma unroll
        for (int kt = 0; kt < 4; kt++) {
            const int kb = kt * 32 + q * 8;
            unsigned v[4];
#pragma unroll
            for (int jj = 0; jj < 4; jj++) {
                unsigned short h0 = 0, h1 = 0;
                const float f0 = We2[kb + 2 * jj];
                const float f1 = We2[kb + 2 * jj + 1];
                if (sub == 0) { h0 = f2bf(f0); h1 = f2bf(f1); }
                else if (sub == 1) {
                    h0 = f2bf(f0 - bf2f(f2bf(f0)));
                    h1 = f2bf(f1 - bf2f(f2bf(f1)));
                }
                v[jj] = (unsigned)h0 | ((unsigned)h1 << 16);
            }
            Bc2[kt] = pack8(v);
        }
    }
    if (t < 128) be1s[t] = be1[t];
    if (t == 128) be2s[0] = be2[0];
    __syncthreads();

    float lnAcc = 0.f;

    for (int tile = (int)blockIdx.x; tile < ntiles; tile += (int)gridDim.x) {
        const int base = tile * 64;
        {
            const int Ei = base + e_;
            unsigned v0 = 0, v1 = 0, v2 = 0, v3 = 0, v4 = 0, v5 = 0, v6 = 0, v7 = 0;
            if (Ei < E) {
                const int s0 = ei[Ei], d0 = ei[E + Ei];
                const float4* ps = (const float4*)(x + (size_t)s0 * D + k0);
                const float4* pd = (const float4*)(x + (size_t)d0 * D + k0);
                const float4 S0 = ps[0], S1 = ps[1], S2 = ps[2], S3 = ps[3];
                const float4 D0 = pd[0], D1 = pd[1], D2 = pd[2], D3 = pd[3];
                v0 = pair_bf(fmaxf(S0.x * D0.x, 0.f), fmaxf(S0.y * D0.y, 0.f));
                v1 = pair_bf(fmaxf(S0.z * D0.z, 0.f), fmaxf(S0.w * D0.w, 0.f));
                v2 = pair_bf(fmaxf(S1.x * D1.x, 0.f), fmaxf(S1.y * D1.y, 0.f));
                v3 = pair_bf(fmaxf(S1.z * D1.z, 0.f), fmaxf(S1.w * D1.w, 0.f));
                v4 = pair_bf(fmaxf(S2.x * D2.x, 0.f), fmaxf(S2.y * D2.y, 0.f));
                v5 = pair_bf(fmaxf(S2.z * D2.z, 0.f), fmaxf(S2.w * D2.w, 0.f));
                v6 = pair_bf(fmaxf(S3.x * D3.x, 0.f), fmaxf(S3.y * D3.y, 0.f));
                v7 = pair_bf(fmaxf(S3.z * D3.z, 0.f), fmaxf(S3.w * D3.w, 0.f));
            }
            const int slot = ((e_ >> 4) * 4 + (ks >> 1)) * 64 + (ks & 1) * 32 + (e_ & 15);
            uint4 u0; u0.x = v0; u0.y = v1; u0.z = v2; u0.w = v3;
            uint4 u1; u1.x = v4; u1.y = v5; u1.z = v6; u1.w = v7;
            *(uint4*)(As + slot * 8) = u0;
            *(uint4*)(As + (slot + 16) * 8) = u1;
        }
        __syncthreads();                    // barrier G
        const int jloc = wv * 16 + sub;
        const float bb = be1s[jloc];
#pragma unroll
        for (int mt = 0; mt < 4; mt++) {
            bf16x8 a0 = *(const bf16x8*)(As + ((mt * 4 + 0) * 64 + l) * 8);
            bf16x8 a1 = *(const bf16x8*)(As + ((mt * 4 + 1) * 64 + l) * 8);
            bf16x8 a2 = *(const bf16x8*)(As + ((mt * 4 + 2) * 64 + l) * 8);
            bf16x8 a3 = *(const bf16x8*)(As + ((mt * 4 + 3) * 64 + l) * 8);
            f32x4 c = {0.f, 0.f, 0.f, 0.f};
            c = __builtin_amdgcn_mfma_f32_16x16x32_bf16(a0, Bh[0], c, 0, 0, 0);
            c = __builtin_amdgcn_mfma_f32_16x16x32_bf16(a1, Bh[1], c, 0, 0, 0);
            c = __builtin_amdgcn_mfma_f32_16x16x32_bf16(a2, Bh[2], c, 0, 0, 0);
            c = __builtin_amdgcn_mfma_f32_16x16x32_bf16(a3, Bh[3], c, 0, 0, 0);
            c = __builtin_amdgcn_mfma_f32_16x16x32_bf16(a0, Bl[0], c, 0, 0, 0);
            c = __builtin_amdgcn_mfma_f32_16x16x32_bf16(a1, Bl[1], c, 0, 0, 0);
            c = __builtin_amdgcn_mfma_f32_16x16x32_bf16(a2, Bl[2], c, 0, 0, 0);
            c = __builtin_amdgcn_mfma_f32_16x16x32_bf16(a3, Bl[3], c, 0, 0, 0);
#pragma unroll
            for (int r = 0; r < 4; r++)
                He[(mt * 16 + q * 4 + r) * 136 + jloc] = f2bf(fmaxf(c[r] + bb, 0.f));
        }
        __syncthreads();                    // barrier M
        if (wv < 4) {
            f32x4 cW = {0.f, 0.f, 0.f, 0.f};
#pragma unroll
            for (int jt = 0; jt < 4; jt++) {
                bf16x8 hf = *(const bf16x8*)(He + (wv * 16 + sub) * 136 + jt * 32 + q * 8);
                cW = __builtin_amdgcn_mfma_f32_16x16x32_bf16(hf, Bc2[jt], cW, 0, 0, 0);
            }
            if (sub < 2) {
#pragma unroll
                for (int r = 0; r < 4; r++)
                    zL[sub * 64 + wv * 16 + q * 4 + r] = cW[r];
            }
        }
        __syncthreads();                    // barrier L
        if (wv == 0) {
            const int Ei = base + l;
            const bool valid = (Ei < E);
            float lossN = 0.f;
            if (valid) {
                const float z = zL[l] + zL[64 + l] + be2s[0];
                const float p = 1.f / (1.f + expf(-z));
                lossN = -fmaxf(log1pf(-p), -100.f);
            }
            const int g = ebatch[Ei < E ? Ei : E - 1];
            seg_atomic(negSum, g, lossN, valid);
            lnAcc += valid ? lossN : 0.f;
        }
    }
    if (wv == 0) wave_add(tot2, lnAcc);
}

__global__ __launch_bounds__(256)
void kl_kernel(const float* __restrict__ xm, const float* __restrict__ xs,
               const int* __restrict__ batch, float* __restrict__ klSum, int N) {
    const int n = (int)(blockIdx.x * 256 + threadIdx.x);
    const bool valid = (n < N);
    float kl = 0.f;
    int g = 0;
    if (valid) {
        const float4* m4 = (const float4*)(xm + (size_t)n * D);
        const float4* s4 = (const float4*)(xs + (size_t)n * D);
        float s = 0.f;
        // Clamp log at -1e4 (< log(min denormal)): bit-identical for sd > 0,
        // finite at sd == 0 where the reference is +inf (threshold inf).
#pragma unroll 8
        for (int i = 0; i < 32; i++) {
            const float4 m = m4[i];
            const float4 sd = s4[i];
            s += 1.f + 2.f * fmaxf(logf(sd.x), -1e4f) - m.x * m.x - sd.x * sd.x;
            s += 1.f + 2.f * fmaxf(logf(sd.y), -1e4f) - m.y * m.y - sd.y * sd.y;
            s += 1.f + 2.f * fmaxf(logf(sd.z), -1e4f) - m.z * m.z - sd.z * sd.z;
            s += 1.f + 2.f * fmaxf(logf(sd.w), -1e4f) - m.w * m.w - sd.w * sd.w;
        }
        kl = -0.5f * s;
        g = batch[n];
    }
    seg_atomic(klSum, g, kl, valid);
}

__global__ __launch_bounds__(256)
void final_kernel(const int* __restrict__ eib, const int* __restrict__ einb,
                  const int* __restrict__ nbatch,
                  const float* __restrict__ posSum, const float* __restrict__ negSum,
                  const float* __restrict__ klSum,
                  float* __restrict__ tot, int E, int N, int G) {
    const int g = (int)(blockIdx.x * blockDim.x + threadIdx.x);
    float lg = 0.f;
    if (g < G) {
        const int cP = lbound(eib, E, g + 1) - lbound(eib, E, g);
        const int cN = lbound(einb, E, g + 1) - lbound(einb, E, g);
        const int cB = lbound(nbatch, N, g + 1) - lbound(nbatch, N, g);
        const float fp = fmaxf((float)cP, 1.f);
        const float fn = fmaxf((float)cN, 1.f);
        const float fb = fmaxf((float)cB, 1.f);
        lg = posSum[g] / fp + negSum[g] / fn + (klSum[g] / fb) / fb;
    }
#pragma unroll
    for (int o = 1; o < 64; o <<= 1) lg += __shfl_xor(lg, o, 64);
    if ((threadIdx.x & 63u) == 0) atomicAdd(tot, lg);
}

__global__ void out_kernel(const float* __restrict__ tot, float* __restrict__ out,
                           int E, int G) {
    if (threadIdx.x == 0 && blockIdx.x == 0) {
        out[0] = tot[0] / (float)G;
        out[1] = 0.5f * (tot[1] / (float)E + tot[2] / (float)E);
    }
}

extern "C" void kernel_launch(void* const* d_in, const int* in_sizes, int n_in,
                              void* d_out, int out_size, void* d_ws, size_t ws_size,
                              hipStream_t stream) {
    const float* x    = (const float*)d_in[0];
    const float* attr = (const float*)d_in[1];
    const float* xm   = (const float*)d_in[2];
    const float* xsd  = (const float*)d_in[3];
    const float* W1   = (const float*)d_in[4];
    const float* b1   = (const float*)d_in[5];
    const float* W2   = (const float*)d_in[6];
    const float* b2   = (const float*)d_in[7];
    const float* We1  = (const float*)d_in[8];
    const float* be1  = (const float*)d_in[9];
    const float* We2  = (const float*)d_in[10];
    const float* be2  = (const float*)d_in[11];
    const int* ei     = (const int*)d_in[12];
    const int* ein    = (const int*)d_in[13];
    const int* eib    = (const int*)d_in[14];
    const int* einb   = (const int*)d_in[15];
    const int* batch  = (const int*)d_in[16];

    const int N = in_sizes[0] / D;       // 100000
    const int E = in_sizes[14];          // 600000
    const int G = 1024;

    float* ws = (float*)d_ws;
    float* posSum = ws;                  // [G]
    float* negSum = ws + G;              // [G]
    float* klSum  = ws + 2 * G;          // [G]
    float* tot    = ws + 3 * G;          // [0]=loss, [1]=sum lep, [2]=sum len

    hipMemsetAsync(d_ws, 0, (size_t)(3 * G + 3) * sizeof(float), stream);

    const int ntiles = (E + 63) / 64;
    const int grid = ntiles < 1024 ? ntiles : 1024;

    pos_kernel<<<grid, 512, 0, stream>>>(x, ei, eib, W1, b1, W2, b2,
                                         We1, be1, We2, be2, attr,
                                         posSum, tot + 1, E, ntiles);
    neg_kernel<<<grid, 512, 0, stream>>>(x, ein, einb, We1, be1, We2, be2,
                                         negSum, tot + 2, E, ntiles);
    kl_kernel<<<(N + 255) / 256, 256, 0, stream>>>(xm, xsd, batch, klSum, N);
    final_kernel<<<(G + 255) / 256, 256, 0, stream>>>(eib, einb, batch,
                                                      posSum, negSum, klSum, tot, E, N, G);
    out_kernel<<<1, 64, 0, stream>>>(tot, (float*)d_out, E, G);
}